// Round 13
// baseline (193.713 us; speedup 1.0000x reference)
//
#include <hip/hip_runtime.h>
#include <hip/hip_bf16.h>

typedef short bf16x8 __attribute__((ext_vector_type(8)));
typedef float f32x4 __attribute__((ext_vector_type(4)));
typedef unsigned short u16x4 __attribute__((ext_vector_type(4)));

#define NQ 600            // B*N
#define D 256
#define NPAR 32768        // G*8192
#define EPS 1e-5f
#define KSPLIT 16         // GEMM2 split-K chunks (2048 each)

// ---------------- workspace layout (bytes) ----------------
#define OFF_OFFS     ((size_t)0)           // 600*384*4 = 921,600
#define OFF_QB       ((size_t)1048576)     // 307,200
#define OFF_H        ((size_t)2097152)     // 600*32768*2 = 39,321,600  (written by sample_mix)
#define OFF_PARAMS   ((size_t)41418752)    // 600*32768*2 = 39,321,600 bf16
#define OFF_KPART    ((size_t)41418752)    // 16*600*256*4 = 9,830,400 — overwrites dead params
#define OFF_WOT      ((size_t)80740352)    // 16,777,216
#define OFF_FEATT    ((size_t)97517568)    // 8*89250*64*2 = 91,392,000 → ends 188,909,568

#define PIX_PER_BG 89250   // 67200 + 16800 + 4200 + 1050

__device__ __forceinline__ void gload_lds16(const void* g, void* l) {
    __builtin_amdgcn_global_load_lds((const __attribute__((address_space(1))) unsigned int*)g,
                                     (__attribute__((address_space(3))) unsigned int*)l,
                                     16, 0, 0);
}
__device__ __forceinline__ float bf2f(unsigned short us) {
    union { unsigned u; float f; } cv; cv.u = ((unsigned)us) << 16; return cv.f;
}
__device__ __forceinline__ unsigned short f2bf(float f) {
    __hip_bfloat16 h = __float2bfloat16(f);
    return *(unsigned short*)&h;
}

// ---------------- prep: feat transform (reg-transpose) + Wot transpose + qb ----------------
// LOW-RESOURCE ONLY (40 VGPR, 4.6KB LDS): r11 showed fusing a heavy path here
// collapses occupancy for the latency-bound feat transform.
__global__ __launch_bounds__(256) void k_prep(
        const float* __restrict__ f0, const float* __restrict__ f1,
        const float* __restrict__ f2, const float* __restrict__ f3,
        const float* __restrict__ W_out, const float* __restrict__ q,
        __hip_bfloat16* __restrict__ featT,
        __hip_bfloat16* __restrict__ Wot, __hip_bfloat16* __restrict__ qb) {
    __shared__ float tile[32][33];
    int bid = blockIdx.x;
    int t = threadIdx.x;
    if (bid < 2792) {
        int bg = bid / 349, wblk = bid % 349;
        int lane = t & 63, w = t >> 6;
        int wid = wblk * 4 + w;   // [0,1396)
        const float* in; int HW, lvloff, wstart;
        if (wid < 1050)      { in = f0; HW = 67200; lvloff = 0;     wstart = 0; }
        else if (wid < 1313) { in = f1; HW = 16800; lvloff = 67200; wstart = 1050; }
        else if (wid < 1379) { in = f2; HW = 4200;  lvloff = 84000; wstart = 1313; }
        else                 { in = f3; HW = 1050;  lvloff = 88200; wstart = 1379; }
        int b = bg >> 2, g = bg & 3;
        int pix = (wid - wstart) * 64 + lane;
        bool ok = pix < HW;
        int pixc = ok ? pix : HW - 1;
        const float* base = in + (size_t)(b * 256 + g * 64) * HW + pixc;
        float v[64];
        #pragma unroll
        for (int c = 0; c < 64; c++) v[c] = base[(size_t)c * HW];
        if (ok) {
            __hip_bfloat16* ob = featT + ((size_t)bg * PIX_PER_BG + lvloff + pixc) * 64;
            #pragma unroll
            for (int s8 = 0; s8 < 8; s8++) {
                unsigned short o[8];
                #pragma unroll
                for (int i = 0; i < 8; i++) o[i] = f2bf(v[s8 * 8 + i]);
                *(bf16x8*)(ob + s8 * 8) = *(bf16x8*)o;
            }
        }
        return;
    }
    int idx = bid - 2792;
    if (idx < 8192) {
        // Wot transpose: W_out [32768][256] f32 -> Wot [256][32768] bf16
        int bx = idx & 7, by = idx >> 3;
        const int R = 32768, C = 256;
        int tx = t & 31, ty = t >> 5;
        int c = bx * 32 + tx;
        #pragma unroll
        for (int i = 0; i < 4; i++) {
            int rr = by * 32 + ty + i * 8;
            tile[ty + i * 8][tx] = W_out[(size_t)rr * C + c];
        }
        __syncthreads();
        int r2 = by * 32 + tx;
        #pragma unroll
        for (int i = 0; i < 4; i++) {
            int c2 = bx * 32 + ty + i * 8;
            Wot[(size_t)c2 * R + r2] = __float2bfloat16(tile[tx][ty + i * 8]);
        }
        return;
    }
    // qb conversion
    int i = (idx - 8192) * 2048 + t * 8;
    float4 v0 = *(const float4*)(q + i);
    float4 v1 = *(const float4*)(q + i + 4);
    unsigned short o[8];
    o[0] = f2bf(v0.x); o[1] = f2bf(v0.y); o[2] = f2bf(v0.z); o[3] = f2bf(v0.w);
    o[4] = f2bf(v1.x); o[5] = f2bf(v1.y); o[6] = f2bf(v1.z); o[7] = f2bf(v1.w);
    *(bf16x8*)(qb + i) = *(bf16x8*)o;
}

// ---------------- GEMM1: offsets (6 blocks) + params (512 blocks) ----------------
// B staged DIRECTLY from f32 W_off/W_param (rows n-contiguous -> coalesced float4),
// f32->bf16 + transpose + swizzle at ds_write time. Each block loops all 5 m-tiles
// so the weight is read from HBM exactly once.
__global__ __launch_bounds__(256) void k_gemm1(const __hip_bfloat16* __restrict__ A,
                              const float* __restrict__ W_off, const float* __restrict__ W_param,
                              const float* __restrict__ b_off, const float* __restrict__ b_param,
                              float* __restrict__ offs, __hip_bfloat16* __restrict__ params) {
    __shared__ __align__(16) char ldsB[32768];   // [n 64][k 512B], slot swz c16^=(n&7)
    int id = blockIdx.x;
    bool isOff = id < 6;
    const float* Wsrc; const float* bias; int n0; size_t C;
    if (isOff) { Wsrc = W_off; bias = b_off; n0 = id * 64; C = 384; }
    else { Wsrc = W_param; bias = b_param; n0 = (id - 6) * 64; C = 32768; }
    int t = threadIdx.x;
    int lane = t & 63, w = t >> 6;
    int la = lane & 15, lb = lane >> 4;

    // stage: 256 k-rows x 64 n-cols
    #pragma unroll
    for (int i = 0; i < 16; i++) {
        int kk = i * 16 + w * 4 + (lane >> 4);
        int j4 = (lane & 15) * 4;
        float4 v = *(const float4*)(Wsrc + (size_t)kk * C + n0 + j4);
        float vv[4] = {v.x, v.y, v.z, v.w};
        #pragma unroll
        for (int u = 0; u < 4; u++) {
            int j = j4 + u;
            int addr = j * 512 + (((kk >> 3) ^ (j & 7)) * 16) + (kk & 7) * 2;
            *(unsigned short*)(ldsB + addr) = f2bf(vv[u]);
        }
    }
    __syncthreads();

    #pragma unroll 1
    for (int mt = 0; mt < 5; mt++) {
        int m0 = mt * 128;
        bf16x8 a[2][8];
        #pragma unroll
        for (int mi = 0; mi < 2; mi++) {
            int row = m0 + w * 32 + mi * 16 + la;
            row = row < NQ ? row : NQ - 1;
            #pragma unroll
            for (int ks = 0; ks < 8; ks++)
                a[mi][ks] = *(const bf16x8*)(A + (size_t)row * 256 + ks * 32 + lb * 8);
        }
        f32x4 acc[2][4];
        #pragma unroll
        for (int i = 0; i < 2; i++)
            #pragma unroll
            for (int j = 0; j < 4; j++) acc[i][j] = (f32x4)(0.f);
        #pragma unroll
        for (int ks = 0; ks < 8; ks++) {
            bf16x8 b[4];
            #pragma unroll
            for (int ni = 0; ni < 4; ni++) {
                int row = ni * 16 + la;
                int c16s = (ks * 4 + lb) ^ (row & 7);
                b[ni] = *(const bf16x8*)(ldsB + row * 512 + c16s * 16);
            }
            #pragma unroll
            for (int mi = 0; mi < 2; mi++)
                #pragma unroll
                for (int ni = 0; ni < 4; ni++)
                    acc[mi][ni] = __builtin_amdgcn_mfma_f32_16x16x32_bf16(a[mi][ks], b[ni], acc[mi][ni], 0, 0, 0);
        }
        #pragma unroll
        for (int mi = 0; mi < 2; mi++) {
            int rbase = m0 + w * 32 + mi * 16 + lb * 4;
            #pragma unroll
            for (int ni = 0; ni < 4; ni++) {
                int col = n0 + ni * 16 + la;
                float bv = bias[col];
                #pragma unroll
                for (int rg = 0; rg < 4; rg++) {
                    int row = rbase + rg;
                    if (row < NQ) {
                        if (isOff) offs[(size_t)row * 384 + col] = acc[mi][ni][rg] + bv;
                        else params[(size_t)row * NPAR + col] = __float2bfloat16(acc[mi][ni][rg] + bv);
                    }
                }
            }
        }
    }
}

// ---------------- fused sample + mix: block per (m,g) ----------------
#define MIX_SMP 0
#define MIX_MT  4096
#define MIX_SS  12288
#define MIX_H1T 20480
__device__ inline float2 blk_reduce2(float s, float ss, float* red, float norm) {
    __syncthreads();
    #pragma unroll
    for (int off = 32; off; off >>= 1) { s += __shfl_down(s, off); ss += __shfl_down(ss, off); }
    int wave = threadIdx.x >> 6, lane = threadIdx.x & 63;
    if (lane == 0) { red[wave * 2] = s; red[wave * 2 + 1] = ss; }
    __syncthreads();
    if (threadIdx.x == 0) {
        float a = 0.f, b = 0.f;
        #pragma unroll
        for (int i = 0; i < 4; i++) { a += red[2 * i]; b += red[2 * i + 1]; }
        red[8] = a * norm; red[9] = b * norm;
    }
    __syncthreads();
    return make_float2(red[8], red[9]);
}

__global__ __launch_bounds__(256) void k_sample_mix(const float* __restrict__ offs,
                      const float* __restrict__ xyzr,
                      const __hip_bfloat16* __restrict__ featT,
                      const __hip_bfloat16* __restrict__ params,
                      __hip_bfloat16* __restrict__ h) {
    __shared__ __align__(16) char lds[24576];
    __shared__ float smeta[32][8];
    __shared__ float red[16];
    int bid = blockIdx.x;
    int m = bid >> 2, g = bid & 3;
    int b = m / 300;
    int t = threadIdx.x;
    int lane = t & 63, w = t >> 6;
    int la = lane & 15, lb = lane >> 4;
    const __hip_bfloat16* pbase = params + (size_t)m * NPAR + g * 8192;

    // stage MT (transpose M): 4096 bf16
    #pragma unroll
    for (int r = 0; r < 2; r++) {
        int i = t + r * 256;
        int c = i >> 3, d0 = (i & 7) * 8;
        bf16x8 v = *(const bf16x8*)(pbase + i * 8);
        #pragma unroll
        for (int j = 0; j < 8; j++) {
            int d = d0 + j;
            int addr = MIX_MT + d * 128 + ((c >> 3) ^ (d & 7)) * 16 + (c & 7) * 2;
            *(unsigned short*)(lds + addr) = ((unsigned short*)&v)[j];
        }
    }
    // stage SS: 4096 bf16
    #pragma unroll
    for (int r = 0; r < 2; r++) {
        int i = t + r * 256;
        int qr = i >> 2, c16 = i & 3;
        bf16x8 v = *(const bf16x8*)(pbase + 4096 + i * 8);
        *(bf16x8*)(lds + MIX_SS + qr * 64 + (c16 ^ (qr & 3)) * 16) = v;
    }
    // sample meta
    if (t < 32) {
        int p = t;
        const float* op = offs + (size_t)m * 384 + (g * 32 + p) * 3;
        float o0 = op[0], o1 = op[1], o2 = op[2];
        float cx = xyzr[m * 4 + 0], cy = xyzr[m * 4 + 1], z = xyzr[m * 4 + 2], rr = xyzr[m * 4 + 3];
        smeta[p][0] = cx + o0 * exp2f(z - 0.5f * rr);
        smeta[p][1] = cy + o1 * exp2f(z + 0.5f * rr);
        float sz = z + o2;
        float e[4], mx = -1e30f;
        #pragma unroll
        for (int l = 0; l < 4; l++) { float d = sz - (float)(2 + l); e[l] = -0.5f * d * d; mx = fmaxf(mx, e[l]); }
        float ssum = 0.f;
        #pragma unroll
        for (int l = 0; l < 4; l++) { e[l] = __expf(e[l] - mx); ssum += e[l]; }
        float inv = 1.f / ssum;
        #pragma unroll
        for (int l = 0; l < 4; l++) smeta[p][2 + l] = e[l] * inv;
    }
    __syncthreads();

    // ---- sample into SMP ----
    int corner = lane >> 4;
    int dx = corner & 1, dy = corner >> 1;
    int ch = (lane & 15) * 4;
    const int Hs[4] = {200, 100, 50, 25};
    const int Ws[4] = {336, 168, 84, 42};
    const int Ls[4] = {0, 67200, 84000, 88200};
    const float invS[4] = {0.25f, 0.125f, 0.0625f, 0.03125f};
    const __hip_bfloat16* base_bg = featT + (size_t)(b * 4 + g) * PIX_PER_BG * 64;
    for (int pi = 0; pi < 8; pi++) {
        int p = w * 8 + pi;
        float sx = smeta[p][0], sy = smeta[p][1];
        float acc0 = 0.f, acc1 = 0.f, acc2 = 0.f, acc3 = 0.f;
        #pragma unroll
        for (int l = 0; l < 4; l++) {
            float wl = smeta[p][2 + l];
            if (wl < 1e-6f) continue;            // wave-uniform
            const int H = Hs[l], W = Ws[l];
            float xp = sx * invS[l] - 0.5f, yp = sy * invS[l] - 0.5f;
            float x0f = floorf(xp), y0f = floorf(yp);
            float wx1 = xp - x0f, wy1 = yp - y0f;
            int xi = (int)x0f + dx, yi = (int)y0f + dy;
            bool valid = (xi >= 0) && (xi < W) && (yi >= 0) && (yi < H);
            int xc = xi < 0 ? 0 : (xi >= W ? W - 1 : xi);
            int yc = yi < 0 ? 0 : (yi >= H ? H - 1 : yi);
            float cw = (dx ? wx1 : 1.f - wx1) * (dy ? wy1 : 1.f - wy1) * wl;
            if (!valid) cw = 0.f;
            const __hip_bfloat16* src = base_bg + ((size_t)Ls[l] + (size_t)yc * W + xc) * 64 + ch;
            u16x4 v = *(const u16x4*)src;
            acc0 += cw * bf2f(v[0]);
            acc1 += cw * bf2f(v[1]);
            acc2 += cw * bf2f(v[2]);
            acc3 += cw * bf2f(v[3]);
        }
        acc0 += __shfl_xor(acc0, 16); acc1 += __shfl_xor(acc1, 16);
        acc2 += __shfl_xor(acc2, 16); acc3 += __shfl_xor(acc3, 16);
        acc0 += __shfl_xor(acc0, 32); acc1 += __shfl_xor(acc1, 32);
        acc2 += __shfl_xor(acc2, 32); acc3 += __shfl_xor(acc3, 32);
        if (lane < 16) {
            unsigned short o[4];
            o[0] = f2bf(acc0); o[1] = f2bf(acc1); o[2] = f2bf(acc2); o[3] = f2bf(acc3);
            int slot = lane >> 1, half = lane & 1;
            *(u16x4*)(lds + MIX_SMP + p * 128 + ((slot ^ (p & 7)) * 16) + half * 8) = *(u16x4*)o;
        }
    }
    __syncthreads();

    // ---- mix: h1 = SMP(32x64) @ M(64x64) ----
    f32x4 acc1v[2];
    acc1v[0] = (f32x4)(0.f); acc1v[1] = (f32x4)(0.f);
    int dcol = w * 16 + la;
    #pragma unroll
    for (int ks = 0; ks < 2; ks++) {
        bf16x8 bfr = *(const bf16x8*)(lds + MIX_MT + dcol * 128 + (((ks * 4 + lb)) ^ (dcol & 7)) * 16);
        #pragma unroll
        for (int mi = 0; mi < 2; mi++) {
            int prow = mi * 16 + la;
            bf16x8 afr = *(const bf16x8*)(lds + MIX_SMP + prow * 128 + ((ks * 4 + lb) ^ (prow & 7)) * 16);
            acc1v[mi] = __builtin_amdgcn_mfma_f32_16x16x32_bf16(afr, bfr, acc1v[mi], 0, 0, 0);
        }
    }
    float s = 0.f, ss = 0.f;
    #pragma unroll
    for (int mi = 0; mi < 2; mi++)
        #pragma unroll
        for (int j = 0; j < 4; j++) { float v = acc1v[mi][j]; s += v; ss += v * v; }
    float2 r1 = blk_reduce2(s, ss, red, 1.f / 2048.f);
    float mu = r1.x, inv = rsqrtf(r1.y - r1.x * r1.x + EPS);
    #pragma unroll
    for (int mi = 0; mi < 2; mi++) {
        u16x4 pk;
        #pragma unroll
        for (int rg = 0; rg < 4; rg++) {
            float v = (acc1v[mi][rg] - mu) * inv;
            pk[rg] = f2bf(v > 0.f ? v : 0.f);
        }
        int c16 = mi * 2 + (lb >> 1);
        int off8 = 8 * (lb & 1);
        *(u16x4*)(lds + MIX_H1T + dcol * 64 + ((c16 ^ (dcol & 3)) * 16) + off8) = pk;
    }
    __syncthreads();

    // ---- h2 = S(128x32) @ h1(32x64) ----
    f32x4 acc2v[8];
    bf16x8 bfr2 = *(const bf16x8*)(lds + MIX_H1T + dcol * 64 + ((lb ^ (dcol & 3)) * 16));
    #pragma unroll
    for (int nj = 0; nj < 8; nj++) {
        int qrow = nj * 16 + la;
        bf16x8 afr = *(const bf16x8*)(lds + MIX_SS + qrow * 64 + ((lb ^ (qrow & 3)) * 16));
        acc2v[nj] = __builtin_amdgcn_mfma_f32_16x16x32_bf16(afr, bfr2, (f32x4)(0.f), 0, 0, 0);
    }
    s = 0.f; ss = 0.f;
    #pragma unroll
    for (int nj = 0; nj < 8; nj++)
        #pragma unroll
        for (int j = 0; j < 4; j++) { float v = acc2v[nj][j]; s += v; ss += v * v; }
    float2 r2 = blk_reduce2(s, ss, red, 1.f / 8192.f);
    float mu2 = r2.x, inv2 = rsqrtf(r2.y - r2.x * r2.x + EPS);
    __hip_bfloat16* hb = h + (size_t)m * NPAR + g * 8192;
    #pragma unroll
    for (int nj = 0; nj < 8; nj++) {
        #pragma unroll
        for (int rg = 0; rg < 4; rg++) {
            int qr = nj * 16 + lb * 4 + rg;
            float v = (acc2v[nj][rg] - mu2) * inv2;
            v = v > 0.f ? v : 0.f;
            hb[qr * 64 + dcol] = __float2bfloat16(v);
        }
    }
}

// ---------------- GEMM2 split-K: BM=64, BN=128, K-chunk 2048 (32 stages), dbuf LDS, XCD swizzle ----------------
__global__ __launch_bounds__(256) void k_gemm_out(const __hip_bfloat16* __restrict__ A,
                           const __hip_bfloat16* __restrict__ Bt, float* __restrict__ kpart) {
    __shared__ __align__(16) char lds[49152];
    int bid = blockIdx.x;
    int work = (bid & 7) * 40 + (bid >> 3);   // 320 blocks, 40 per XCD, bijective
    int mblk = work % 10;
    int nz = work / 10;
    int n0 = (nz & 1) * 128;
    int z = nz >> 1;                          // [0,16)
    int m0 = mblk * 64;
    size_t k0 = (size_t)z * 2048;
    int t = threadIdx.x, lane = t & 63, w = t >> 6;
    int la = lane & 15, lb = lane >> 4;
    int wm = w >> 1, wn = w & 1;

    const char* Ag = (const char*)A;
    const char* Bg = (const char*)Bt;

    auto stage = [&](int buf, int st) {
        size_t kk = k0 + (size_t)st * 64;
        char* dstA = lds + buf * 24576;
        char* dstB = dstA + 8192;
        #pragma unroll
        for (int r = 0; r < 2; r++) {
            int p = (r * 4 + w) * 64 + lane;
            int row = p >> 3, c16 = p & 7;
            int c16s = c16 ^ (row & 7);
            int grow = m0 + row; grow = grow < NQ ? grow : NQ - 1;
            gload_lds16(Ag + ((size_t)grow * NPAR + kk) * 2 + c16s * 16, dstA + p * 16);
        }
        #pragma unroll
        for (int r = 0; r < 4; r++) {
            int p = (r * 4 + w) * 64 + lane;
            int row = p >> 3, c16 = p & 7;
            int c16s = c16 ^ (row & 7);
            gload_lds16(Bg + ((size_t)(n0 + row) * NPAR + kk) * 2 + c16s * 16, dstB + p * 16);
        }
    };

    f32x4 acc[2][4];
    #pragma unroll
    for (int i = 0; i < 2; i++)
        #pragma unroll
        for (int j = 0; j < 4; j++) acc[i][j] = (f32x4)(0.f);

    stage(0, 0);
    __syncthreads();
    for (int st = 0; st < 32; st++) {
        int buf = st & 1;
        if (st < 31) stage(buf ^ 1, st + 1);
        const char* tA = lds + buf * 24576;
        const char* tB = tA + 8192;
        #pragma unroll
        for (int ks = 0; ks < 2; ks++) {
            bf16x8 a[2], b[4];
            #pragma unroll
            for (int mi = 0; mi < 2; mi++) {
                int row = wm * 32 + mi * 16 + la;
                int c16s = (ks * 4 + lb) ^ (row & 7);
                a[mi] = *(const bf16x8*)(tA + row * 128 + c16s * 16);
            }
            #pragma unroll
            for (int ni = 0; ni < 4; ni++) {
                int row = wn * 64 + ni * 16 + la;
                int c16s = (ks * 4 + lb) ^ (row & 7);
                b[ni] = *(const bf16x8*)(tB + row * 128 + c16s * 16);
            }
            #pragma unroll
            for (int mi = 0; mi < 2; mi++)
                #pragma unroll
                for (int ni = 0; ni < 4; ni++)
                    acc[mi][ni] = __builtin_amdgcn_mfma_f32_16x16x32_bf16(a[mi], b[ni], acc[mi][ni], 0, 0, 0);
        }
        __syncthreads();
    }

    float* outp = kpart + (size_t)z * (NQ * D);
    #pragma unroll
    for (int mi = 0; mi < 2; mi++) {
        int rbase = m0 + wm * 32 + mi * 16 + lb * 4;
        #pragma unroll
        for (int ni = 0; ni < 4; ni++) {
            int col = n0 + wn * 64 + ni * 16 + la;
            #pragma unroll
            for (int rg = 0; rg < 4; rg++) {
                int row = rbase + rg;
                if (row < NQ) outp[(size_t)row * D + col] = acc[mi][ni][rg];
            }
        }
    }
}

// ---------------- final: sum partials + residual + bias, LayerNorm ----------------
__global__ void k_ln_out(const float* __restrict__ kpart, const float* __restrict__ queries,
                         const float* __restrict__ b_out, const float* __restrict__ gamma,
                         const float* __restrict__ beta, float* __restrict__ out) {
    int m = blockIdx.x, t = threadIdx.x;
    float x = queries[m * 256 + t] + b_out[t];
    for (int kc = 0; kc < KSPLIT; kc++) x += kpart[(size_t)kc * (NQ * D) + m * 256 + t];
    __shared__ float red[16];
    float s = x, ss = x * x;
    #pragma unroll
    for (int off = 32; off; off >>= 1) { s += __shfl_down(s, off); ss += __shfl_down(ss, off); }
    int wave = t >> 6, lane = t & 63;
    if (lane == 0) { red[wave * 2] = s; red[wave * 2 + 1] = ss; }
    __syncthreads();
    if (t == 0) {
        float a = 0.f, b = 0.f;
        #pragma unroll
        for (int i = 0; i < 4; i++) { a += red[2 * i]; b += red[2 * i + 1]; }
        red[8] = a * (1.f / 256.f); red[9] = b * (1.f / 256.f);
    }
    __syncthreads();
    float mu = red[8], var = red[9] - mu * mu;
    float inv = rsqrtf(var + EPS);
    out[m * 256 + t] = (x - mu) * inv * gamma[t] + beta[t];
}

extern "C" void kernel_launch(void* const* d_in, const int* in_sizes, int n_in,
                              void* d_out, int out_size, void* d_ws, size_t ws_size,
                              hipStream_t stream) {
    const float* queries = (const float*)d_in[0];
    const float* xyzr    = (const float*)d_in[1];
    const float* f0      = (const float*)d_in[2];
    const float* f1      = (const float*)d_in[3];
    const float* f2      = (const float*)d_in[4];
    const float* f3      = (const float*)d_in[5];
    const float* W_off   = (const float*)d_in[6];
    const float* b_off   = (const float*)d_in[7];
    const float* W_param = (const float*)d_in[8];
    const float* b_param = (const float*)d_in[9];
    const float* W_out   = (const float*)d_in[10];
    const float* b_out   = (const float*)d_in[11];
    const float* gamma   = (const float*)d_in[12];
    const float* beta    = (const float*)d_in[13];
    float* out = (float*)d_out;
    char* ws = (char*)d_ws;

    float* offs            = (float*)(ws + OFF_OFFS);
    __hip_bfloat16* qb     = (__hip_bfloat16*)(ws + OFF_QB);
    __hip_bfloat16* hbuf   = (__hip_bfloat16*)(ws + OFF_H);
    __hip_bfloat16* params = (__hip_bfloat16*)(ws + OFF_PARAMS);
    float* kpart           = (float*)(ws + OFF_KPART);
    __hip_bfloat16* Wot    = (__hip_bfloat16*)(ws + OFF_WOT);
    __hip_bfloat16* featT  = (__hip_bfloat16*)(ws + OFF_FEATT);

    k_prep<<<11059, 256, 0, stream>>>(f0, f1, f2, f3, W_out, queries, featT, Wot, qb);
    k_gemm1<<<518, 256, 0, stream>>>(qb, W_off, W_param, b_off, b_param, offs, params);
    k_sample_mix<<<2400, 256, 0, stream>>>(offs, xyzr, featT, params, hbuf);
    k_gemm_out<<<320, 256, 0, stream>>>(hbuf, Wot, kpart);
    k_ln_out<<<600, 256, 0, stream>>>(kpart, queries, b_out, gamma, beta, out);
}

// Round 15
// 188.673 us; speedup vs baseline: 1.0267x; 1.0267x over previous
//
#include <hip/hip_runtime.h>
#include <hip/hip_bf16.h>

typedef short bf16x8 __attribute__((ext_vector_type(8)));
typedef float f32x4 __attribute__((ext_vector_type(4)));
typedef unsigned short u16x4 __attribute__((ext_vector_type(4)));

#define NQ 600            // B*N
#define D 256
#define NPAR 32768        // G*8192
#define EPS 1e-5f
#define KSPLIT 32         // GEMM2 split-K chunks (1024 each)

// ---------------- workspace layout (bytes) ----------------
#define OFF_OFFS     ((size_t)0)           // 600*384*4 = 921,600
#define OFF_QB       ((size_t)1048576)     // 307,200
#define OFF_H        ((size_t)2097152)     // 600*32768*2 = 39,321,600  (written by sample_mix)
#define OFF_PARAMS   ((size_t)41418752)    // 600*32768*2 = 39,321,600 bf16
#define OFF_KPART    ((size_t)41418752)    // 32*600*256*4 = 19,660,800 — overwrites dead params
#define OFF_WOT      ((size_t)80740352)    // 16,777,216
#define OFF_FEATT    ((size_t)97517568)    // 8*89250*64*2 = 91,392,000 → ends 188,909,568

#define PIX_PER_BG 89250   // 67200 + 16800 + 4200 + 1050

__device__ __forceinline__ void gload_lds16(const void* g, void* l) {
    __builtin_amdgcn_global_load_lds((const __attribute__((address_space(1))) unsigned int*)g,
                                     (__attribute__((address_space(3))) unsigned int*)l,
                                     16, 0, 0);
}
__device__ __forceinline__ float bf2f(unsigned short us) {
    union { unsigned u; float f; } cv; cv.u = ((unsigned)us) << 16; return cv.f;
}
__device__ __forceinline__ unsigned short f2bf(float f) {
    __hip_bfloat16 h = __float2bfloat16(f);
    return *(unsigned short*)&h;
}

// ---------------- prep: feat transform (reg-transpose) + Wot transpose + qb ----------------
// LOW-RESOURCE ONLY (40 VGPR, 4.6KB LDS): r11 showed fusing a heavy path here
// collapses occupancy for the latency-bound feat transform.
__global__ __launch_bounds__(256) void k_prep(
        const float* __restrict__ f0, const float* __restrict__ f1,
        const float* __restrict__ f2, const float* __restrict__ f3,
        const float* __restrict__ W_out, const float* __restrict__ q,
        __hip_bfloat16* __restrict__ featT,
        __hip_bfloat16* __restrict__ Wot, __hip_bfloat16* __restrict__ qb) {
    __shared__ float tile[32][33];
    int bid = blockIdx.x;
    int t = threadIdx.x;
    if (bid < 2792) {
        int bg = bid / 349, wblk = bid % 349;
        int lane = t & 63, w = t >> 6;
        int wid = wblk * 4 + w;   // [0,1396)
        const float* in; int HW, lvloff, wstart;
        if (wid < 1050)      { in = f0; HW = 67200; lvloff = 0;     wstart = 0; }
        else if (wid < 1313) { in = f1; HW = 16800; lvloff = 67200; wstart = 1050; }
        else if (wid < 1379) { in = f2; HW = 4200;  lvloff = 84000; wstart = 1313; }
        else                 { in = f3; HW = 1050;  lvloff = 88200; wstart = 1379; }
        int b = bg >> 2, g = bg & 3;
        int pix = (wid - wstart) * 64 + lane;
        bool ok = pix < HW;
        int pixc = ok ? pix : HW - 1;
        const float* base = in + (size_t)(b * 256 + g * 64) * HW + pixc;
        float v[64];
        #pragma unroll
        for (int c = 0; c < 64; c++) v[c] = base[(size_t)c * HW];
        if (ok) {
            __hip_bfloat16* ob = featT + ((size_t)bg * PIX_PER_BG + lvloff + pixc) * 64;
            #pragma unroll
            for (int s8 = 0; s8 < 8; s8++) {
                unsigned short o[8];
                #pragma unroll
                for (int i = 0; i < 8; i++) o[i] = f2bf(v[s8 * 8 + i]);
                *(bf16x8*)(ob + s8 * 8) = *(bf16x8*)o;
            }
        }
        return;
    }
    int idx = bid - 2792;
    if (idx < 8192) {
        // Wot transpose: W_out [32768][256] f32 -> Wot [256][32768] bf16
        int bx = idx & 7, by = idx >> 3;
        const int R = 32768, C = 256;
        int tx = t & 31, ty = t >> 5;
        int c = bx * 32 + tx;
        #pragma unroll
        for (int i = 0; i < 4; i++) {
            int rr = by * 32 + ty + i * 8;
            tile[ty + i * 8][tx] = W_out[(size_t)rr * C + c];
        }
        __syncthreads();
        int r2 = by * 32 + tx;
        #pragma unroll
        for (int i = 0; i < 4; i++) {
            int c2 = bx * 32 + ty + i * 8;
            Wot[(size_t)c2 * R + r2] = __float2bfloat16(tile[tx][ty + i * 8]);
        }
        return;
    }
    // qb conversion
    int i = (idx - 8192) * 2048 + t * 8;
    float4 v0 = *(const float4*)(q + i);
    float4 v1 = *(const float4*)(q + i + 4);
    unsigned short o[8];
    o[0] = f2bf(v0.x); o[1] = f2bf(v0.y); o[2] = f2bf(v0.z); o[3] = f2bf(v0.w);
    o[4] = f2bf(v1.x); o[5] = f2bf(v1.y); o[6] = f2bf(v1.z); o[7] = f2bf(v1.w);
    *(bf16x8*)(qb + i) = *(bf16x8*)o;
}

// ---------------- GEMM1: offsets (6 blocks) + params (512 blocks) ----------------
// B staged DIRECTLY from f32 W_off/W_param (rows n-contiguous -> coalesced float4),
// f32->bf16 + transpose + swizzle at ds_write time. Each block loops all 5 m-tiles
// so the weight is read from HBM exactly once.
__global__ __launch_bounds__(256) void k_gemm1(const __hip_bfloat16* __restrict__ A,
                              const float* __restrict__ W_off, const float* __restrict__ W_param,
                              const float* __restrict__ b_off, const float* __restrict__ b_param,
                              float* __restrict__ offs, __hip_bfloat16* __restrict__ params) {
    __shared__ __align__(16) char ldsB[32768];   // [n 64][k 512B], slot swz c16^=(n&7)
    int id = blockIdx.x;
    bool isOff = id < 6;
    const float* Wsrc; const float* bias; int n0; size_t C;
    if (isOff) { Wsrc = W_off; bias = b_off; n0 = id * 64; C = 384; }
    else { Wsrc = W_param; bias = b_param; n0 = (id - 6) * 64; C = 32768; }
    int t = threadIdx.x;
    int lane = t & 63, w = t >> 6;
    int la = lane & 15, lb = lane >> 4;

    // stage: 256 k-rows x 64 n-cols
    #pragma unroll
    for (int i = 0; i < 16; i++) {
        int kk = i * 16 + w * 4 + (lane >> 4);
        int j4 = (lane & 15) * 4;
        float4 v = *(const float4*)(Wsrc + (size_t)kk * C + n0 + j4);
        float vv[4] = {v.x, v.y, v.z, v.w};
        #pragma unroll
        for (int u = 0; u < 4; u++) {
            int j = j4 + u;
            int addr = j * 512 + (((kk >> 3) ^ (j & 7)) * 16) + (kk & 7) * 2;
            *(unsigned short*)(ldsB + addr) = f2bf(vv[u]);
        }
    }
    __syncthreads();

    #pragma unroll 1
    for (int mt = 0; mt < 5; mt++) {
        int m0 = mt * 128;
        bf16x8 a[2][8];
        #pragma unroll
        for (int mi = 0; mi < 2; mi++) {
            int row = m0 + w * 32 + mi * 16 + la;
            row = row < NQ ? row : NQ - 1;
            #pragma unroll
            for (int ks = 0; ks < 8; ks++)
                a[mi][ks] = *(const bf16x8*)(A + (size_t)row * 256 + ks * 32 + lb * 8);
        }
        f32x4 acc[2][4];
        #pragma unroll
        for (int i = 0; i < 2; i++)
            #pragma unroll
            for (int j = 0; j < 4; j++) acc[i][j] = (f32x4)(0.f);
        #pragma unroll
        for (int ks = 0; ks < 8; ks++) {
            bf16x8 b[4];
            #pragma unroll
            for (int ni = 0; ni < 4; ni++) {
                int row = ni * 16 + la;
                int c16s = (ks * 4 + lb) ^ (row & 7);
                b[ni] = *(const bf16x8*)(ldsB + row * 512 + c16s * 16);
            }
            #pragma unroll
            for (int mi = 0; mi < 2; mi++)
                #pragma unroll
                for (int ni = 0; ni < 4; ni++)
                    acc[mi][ni] = __builtin_amdgcn_mfma_f32_16x16x32_bf16(a[mi][ks], b[ni], acc[mi][ni], 0, 0, 0);
        }
        #pragma unroll
        for (int mi = 0; mi < 2; mi++) {
            int rbase = m0 + w * 32 + mi * 16 + lb * 4;
            #pragma unroll
            for (int ni = 0; ni < 4; ni++) {
                int col = n0 + ni * 16 + la;
                float bv = bias[col];
                #pragma unroll
                for (int rg = 0; rg < 4; rg++) {
                    int row = rbase + rg;
                    if (row < NQ) {
                        if (isOff) offs[(size_t)row * 384 + col] = acc[mi][ni][rg] + bv;
                        else params[(size_t)row * NPAR + col] = __float2bfloat16(acc[mi][ni][rg] + bv);
                    }
                }
            }
        }
    }
}

// ---------------- fused sample + mix: block per (m,g) ----------------
#define MIX_SMP 0
#define MIX_MT  4096
#define MIX_SS  12288
#define MIX_H1T 20480
__device__ inline float2 blk_reduce2(float s, float ss, float* red, float norm) {
    __syncthreads();
    #pragma unroll
    for (int off = 32; off; off >>= 1) { s += __shfl_down(s, off); ss += __shfl_down(ss, off); }
    int wave = threadIdx.x >> 6, lane = threadIdx.x & 63;
    if (lane == 0) { red[wave * 2] = s; red[wave * 2 + 1] = ss; }
    __syncthreads();
    if (threadIdx.x == 0) {
        float a = 0.f, b = 0.f;
        #pragma unroll
        for (int i = 0; i < 4; i++) { a += red[2 * i]; b += red[2 * i + 1]; }
        red[8] = a * norm; red[9] = b * norm;
    }
    __syncthreads();
    return make_float2(red[8], red[9]);
}

__global__ __launch_bounds__(256) void k_sample_mix(const float* __restrict__ offs,
                      const float* __restrict__ xyzr,
                      const __hip_bfloat16* __restrict__ featT,
                      const __hip_bfloat16* __restrict__ params,
                      __hip_bfloat16* __restrict__ h) {
    __shared__ __align__(16) char lds[24576];
    __shared__ float smeta[32][8];
    __shared__ float red[16];
    int bid = blockIdx.x;
    int m = bid >> 2, g = bid & 3;
    int b = m / 300;
    int t = threadIdx.x;
    int lane = t & 63, w = t >> 6;
    int la = lane & 15, lb = lane >> 4;
    const __hip_bfloat16* pbase = params + (size_t)m * NPAR + g * 8192;

    // stage MT (transpose M): 4096 bf16
    #pragma unroll
    for (int r = 0; r < 2; r++) {
        int i = t + r * 256;
        int c = i >> 3, d0 = (i & 7) * 8;
        bf16x8 v = *(const bf16x8*)(pbase + i * 8);
        #pragma unroll
        for (int j = 0; j < 8; j++) {
            int d = d0 + j;
            int addr = MIX_MT + d * 128 + ((c >> 3) ^ (d & 7)) * 16 + (c & 7) * 2;
            *(unsigned short*)(lds + addr) = ((unsigned short*)&v)[j];
        }
    }
    // stage SS: 4096 bf16
    #pragma unroll
    for (int r = 0; r < 2; r++) {
        int i = t + r * 256;
        int qr = i >> 2, c16 = i & 3;
        bf16x8 v = *(const bf16x8*)(pbase + 4096 + i * 8);
        *(bf16x8*)(lds + MIX_SS + qr * 64 + (c16 ^ (qr & 3)) * 16) = v;
    }
    // sample meta
    if (t < 32) {
        int p = t;
        const float* op = offs + (size_t)m * 384 + (g * 32 + p) * 3;
        float o0 = op[0], o1 = op[1], o2 = op[2];
        float cx = xyzr[m * 4 + 0], cy = xyzr[m * 4 + 1], z = xyzr[m * 4 + 2], rr = xyzr[m * 4 + 3];
        smeta[p][0] = cx + o0 * exp2f(z - 0.5f * rr);
        smeta[p][1] = cy + o1 * exp2f(z + 0.5f * rr);
        float sz = z + o2;
        float e[4], mx = -1e30f;
        #pragma unroll
        for (int l = 0; l < 4; l++) { float d = sz - (float)(2 + l); e[l] = -0.5f * d * d; mx = fmaxf(mx, e[l]); }
        float ssum = 0.f;
        #pragma unroll
        for (int l = 0; l < 4; l++) { e[l] = __expf(e[l] - mx); ssum += e[l]; }
        float inv = 1.f / ssum;
        #pragma unroll
        for (int l = 0; l < 4; l++) smeta[p][2 + l] = e[l] * inv;
    }
    __syncthreads();

    // ---- sample into SMP ----
    int corner = lane >> 4;
    int dx = corner & 1, dy = corner >> 1;
    int ch = (lane & 15) * 4;
    const int Hs[4] = {200, 100, 50, 25};
    const int Ws[4] = {336, 168, 84, 42};
    const int Ls[4] = {0, 67200, 84000, 88200};
    const float invS[4] = {0.25f, 0.125f, 0.0625f, 0.03125f};
    const __hip_bfloat16* base_bg = featT + (size_t)(b * 4 + g) * PIX_PER_BG * 64;
    for (int pi = 0; pi < 8; pi++) {
        int p = w * 8 + pi;
        float sx = smeta[p][0], sy = smeta[p][1];
        float acc0 = 0.f, acc1 = 0.f, acc2 = 0.f, acc3 = 0.f;
        #pragma unroll
        for (int l = 0; l < 4; l++) {
            float wl = smeta[p][2 + l];
            if (wl < 1e-6f) continue;            // wave-uniform
            const int H = Hs[l], W = Ws[l];
            float xp = sx * invS[l] - 0.5f, yp = sy * invS[l] - 0.5f;
            float x0f = floorf(xp), y0f = floorf(yp);
            float wx1 = xp - x0f, wy1 = yp - y0f;
            int xi = (int)x0f + dx, yi = (int)y0f + dy;
            bool valid = (xi >= 0) && (xi < W) && (yi >= 0) && (yi < H);
            int xc = xi < 0 ? 0 : (xi >= W ? W - 1 : xi);
            int yc = yi < 0 ? 0 : (yi >= H ? H - 1 : yi);
            float cw = (dx ? wx1 : 1.f - wx1) * (dy ? wy1 : 1.f - wy1) * wl;
            if (!valid) cw = 0.f;
            const __hip_bfloat16* src = base_bg + ((size_t)Ls[l] + (size_t)yc * W + xc) * 64 + ch;
            u16x4 v = *(const u16x4*)src;
            acc0 += cw * bf2f(v[0]);
            acc1 += cw * bf2f(v[1]);
            acc2 += cw * bf2f(v[2]);
            acc3 += cw * bf2f(v[3]);
        }
        acc0 += __shfl_xor(acc0, 16); acc1 += __shfl_xor(acc1, 16);
        acc2 += __shfl_xor(acc2, 16); acc3 += __shfl_xor(acc3, 16);
        acc0 += __shfl_xor(acc0, 32); acc1 += __shfl_xor(acc1, 32);
        acc2 += __shfl_xor(acc2, 32); acc3 += __shfl_xor(acc3, 32);
        if (lane < 16) {
            unsigned short o[4];
            o[0] = f2bf(acc0); o[1] = f2bf(acc1); o[2] = f2bf(acc2); o[3] = f2bf(acc3);
            int slot = lane >> 1, half = lane & 1;
            *(u16x4*)(lds + MIX_SMP + p * 128 + ((slot ^ (p & 7)) * 16) + half * 8) = *(u16x4*)o;
        }
    }
    __syncthreads();

    // ---- mix: h1 = SMP(32x64) @ M(64x64) ----
    f32x4 acc1v[2];
    acc1v[0] = (f32x4)(0.f); acc1v[1] = (f32x4)(0.f);
    int dcol = w * 16 + la;
    #pragma unroll
    for (int ks = 0; ks < 2; ks++) {
        bf16x8 bfr = *(const bf16x8*)(lds + MIX_MT + dcol * 128 + (((ks * 4 + lb)) ^ (dcol & 7)) * 16);
        #pragma unroll
        for (int mi = 0; mi < 2; mi++) {
            int prow = mi * 16 + la;
            bf16x8 afr = *(const bf16x8*)(lds + MIX_SMP + prow * 128 + ((ks * 4 + lb) ^ (prow & 7)) * 16);
            acc1v[mi] = __builtin_amdgcn_mfma_f32_16x16x32_bf16(afr, bfr, acc1v[mi], 0, 0, 0);
        }
    }
    float s = 0.f, ss = 0.f;
    #pragma unroll
    for (int mi = 0; mi < 2; mi++)
        #pragma unroll
        for (int j = 0; j < 4; j++) { float v = acc1v[mi][j]; s += v; ss += v * v; }
    float2 r1 = blk_reduce2(s, ss, red, 1.f / 2048.f);
    float mu = r1.x, inv = rsqrtf(r1.y - r1.x * r1.x + EPS);
    #pragma unroll
    for (int mi = 0; mi < 2; mi++) {
        u16x4 pk;
        #pragma unroll
        for (int rg = 0; rg < 4; rg++) {
            float v = (acc1v[mi][rg] - mu) * inv;
            pk[rg] = f2bf(v > 0.f ? v : 0.f);
        }
        int c16 = mi * 2 + (lb >> 1);
        int off8 = 8 * (lb & 1);
        *(u16x4*)(lds + MIX_H1T + dcol * 64 + ((c16 ^ (dcol & 3)) * 16) + off8) = pk;
    }
    __syncthreads();

    // ---- h2 = S(128x32) @ h1(32x64) ----
    f32x4 acc2v[8];
    bf16x8 bfr2 = *(const bf16x8*)(lds + MIX_H1T + dcol * 64 + ((lb ^ (dcol & 3)) * 16));
    #pragma unroll
    for (int nj = 0; nj < 8; nj++) {
        int qrow = nj * 16 + la;
        bf16x8 afr = *(const bf16x8*)(lds + MIX_SS + qrow * 64 + ((lb ^ (qrow & 3)) * 16));
        acc2v[nj] = __builtin_amdgcn_mfma_f32_16x16x32_bf16(afr, bfr2, (f32x4)(0.f), 0, 0, 0);
    }
    s = 0.f; ss = 0.f;
    #pragma unroll
    for (int nj = 0; nj < 8; nj++)
        #pragma unroll
        for (int j = 0; j < 4; j++) { float v = acc2v[nj][j]; s += v; ss += v * v; }
    float2 r2 = blk_reduce2(s, ss, red, 1.f / 8192.f);
    float mu2 = r2.x, inv2 = rsqrtf(r2.y - r2.x * r2.x + EPS);
    __hip_bfloat16* hb = h + (size_t)m * NPAR + g * 8192;
    #pragma unroll
    for (int nj = 0; nj < 8; nj++) {
        #pragma unroll
        for (int rg = 0; rg < 4; rg++) {
            int qr = nj * 16 + lb * 4 + rg;
            float v = (acc2v[nj][rg] - mu2) * inv2;
            v = v > 0.f ? v : 0.f;
            hb[qr * 64 + dcol] = __float2bfloat16(v);
        }
    }
}

// ---------------- GEMM2 split-K: BM=64, BN=128, K-chunk 1024, dbuf LDS, XCD-chunked swizzle ----------------
// grid 640 = 10 m x 2 n x 32 z; swizzle (bid&7)*80+(bid>>3) is bijective over [0,640).
__global__ __launch_bounds__(256) void k_gemm_out(const __hip_bfloat16* __restrict__ A,
                           const __hip_bfloat16* __restrict__ Bt, float* __restrict__ kpart) {
    __shared__ __align__(16) char lds[49152];
    int bid = blockIdx.x;
    int work = (bid & 7) * 80 + (bid >> 3);
    int mblk = work % 10;
    int nz = work / 10;
    int n0 = (nz & 1) * 128;
    int z = nz >> 1;
    int m0 = mblk * 64;
    size_t k0 = (size_t)z * 1024;
    int t = threadIdx.x, lane = t & 63, w = t >> 6;
    int la = lane & 15, lb = lane >> 4;
    int wm = w >> 1, wn = w & 1;

    const char* Ag = (const char*)A;
    const char* Bg = (const char*)Bt;

    auto stage = [&](int buf, int st) {
        size_t kk = k0 + (size_t)st * 64;
        char* dstA = lds + buf * 24576;
        char* dstB = dstA + 8192;
        #pragma unroll
        for (int r = 0; r < 2; r++) {
            int p = (r * 4 + w) * 64 + lane;
            int row = p >> 3, c16 = p & 7;
            int c16s = c16 ^ (row & 7);
            int grow = m0 + row; grow = grow < NQ ? grow : NQ - 1;
            gload_lds16(Ag + ((size_t)grow * NPAR + kk) * 2 + c16s * 16, dstA + p * 16);
        }
        #pragma unroll
        for (int r = 0; r < 4; r++) {
            int p = (r * 4 + w) * 64 + lane;
            int row = p >> 3, c16 = p & 7;
            int c16s = c16 ^ (row & 7);
            gload_lds16(Bg + ((size_t)(n0 + row) * NPAR + kk) * 2 + c16s * 16, dstB + p * 16);
        }
    };

    f32x4 acc[2][4];
    #pragma unroll
    for (int i = 0; i < 2; i++)
        #pragma unroll
        for (int j = 0; j < 4; j++) acc[i][j] = (f32x4)(0.f);

    stage(0, 0);
    __syncthreads();
    for (int st = 0; st < 16; st++) {
        int buf = st & 1;
        if (st < 15) stage(buf ^ 1, st + 1);
        const char* tA = lds + buf * 24576;
        const char* tB = tA + 8192;
        #pragma unroll
        for (int ks = 0; ks < 2; ks++) {
            bf16x8 a[2], b[4];
            #pragma unroll
            for (int mi = 0; mi < 2; mi++) {
                int row = wm * 32 + mi * 16 + la;
                int c16s = (ks * 4 + lb) ^ (row & 7);
                a[mi] = *(const bf16x8*)(tA + row * 128 + c16s * 16);
            }
            #pragma unroll
            for (int ni = 0; ni < 4; ni++) {
                int row = wn * 64 + ni * 16 + la;
                int c16s = (ks * 4 + lb) ^ (row & 7);
                b[ni] = *(const bf16x8*)(tB + row * 128 + c16s * 16);
            }
            #pragma unroll
            for (int mi = 0; mi < 2; mi++)
                #pragma unroll
                for (int ni = 0; ni < 4; ni++)
                    acc[mi][ni] = __builtin_amdgcn_mfma_f32_16x16x32_bf16(a[mi], b[ni], acc[mi][ni], 0, 0, 0);
        }
        __syncthreads();
    }

    float* outp = kpart + (size_t)z * (NQ * D);
    #pragma unroll
    for (int mi = 0; mi < 2; mi++) {
        int rbase = m0 + wm * 32 + mi * 16 + lb * 4;
        #pragma unroll
        for (int ni = 0; ni < 4; ni++) {
            int col = n0 + wn * 64 + ni * 16 + la;
            #pragma unroll
            for (int rg = 0; rg < 4; rg++) {
                int row = rbase + rg;
                if (row < NQ) outp[(size_t)row * D + col] = acc[mi][ni][rg];
            }
        }
    }
}

// ---------------- final: sum partials + residual + bias, LayerNorm ----------------
__global__ void k_ln_out(const float* __restrict__ kpart, const float* __restrict__ queries,
                         const float* __restrict__ b_out, const float* __restrict__ gamma,
                         const float* __restrict__ beta, float* __restrict__ out) {
    int m = blockIdx.x, t = threadIdx.x;
    float x = queries[m * 256 + t] + b_out[t];
    for (int kc = 0; kc < KSPLIT; kc++) x += kpart[(size_t)kc * (NQ * D) + m * 256 + t];
    __shared__ float red[16];
    float s = x, ss = x * x;
    #pragma unroll
    for (int off = 32; off; off >>= 1) { s += __shfl_down(s, off); ss += __shfl_down(ss, off); }
    int wave = t >> 6, lane = t & 63;
    if (lane == 0) { red[wave * 2] = s; red[wave * 2 + 1] = ss; }
    __syncthreads();
    if (t == 0) {
        float a = 0.f, b = 0.f;
        #pragma unroll
        for (int i = 0; i < 4; i++) { a += red[2 * i]; b += red[2 * i + 1]; }
        red[8] = a * (1.f / 256.f); red[9] = b * (1.f / 256.f);
    }
    __syncthreads();
    float mu = red[8], var = red[9] - mu * mu;
    float inv = rsqrtf(var + EPS);
    out[m * 256 + t] = (x - mu) * inv * gamma[t] + beta[t];
}

extern "C" void kernel_launch(void* const* d_in, const int* in_sizes, int n_in,
                              void* d_out, int out_size, void* d_ws, size_t ws_size,
                              hipStream_t stream) {
    const float* queries = (const float*)d_in[0];
    const float* xyzr    = (const float*)d_in[1];
    const float* f0      = (const float*)d_in[2];
    const float* f1      = (const float*)d_in[3];
    const float* f2      = (const float*)d_in[4];
    const float* f3      = (const float*)d_in[5];
    const float* W_off   = (const float*)d_in[6];
    const float* b_off   = (const float*)d_in[7];
    const float* W_param = (const float*)d_in[8];
    const float* b_param = (const float*)d_in[9];
    const float* W_out   = (const float*)d_in[10];
    const float* b_out   = (const float*)d_in[11];
    const float* gamma   = (const float*)d_in[12];
    const float* beta    = (const float*)d_in[13];
    float* out = (float*)d_out;
    char* ws = (char*)d_ws;

    float* offs            = (float*)(ws + OFF_OFFS);
    __hip_bfloat16* qb     = (__hip_bfloat16*)(ws + OFF_QB);
    __hip_bfloat16* hbuf   = (__hip_bfloat16*)(ws + OFF_H);
    __hip_bfloat16* params = (__hip_bfloat16*)(ws + OFF_PARAMS);
    float* kpart           = (float*)(ws + OFF_KPART);
    __hip_bfloat16* Wot    = (__hip_bfloat16*)(ws + OFF_WOT);
    __hip_bfloat16* featT  = (__hip_bfloat16*)(ws + OFF_FEATT);

    k_prep<<<11059, 256, 0, stream>>>(f0, f1, f2, f3, W_out, queries, featT, Wot, qb);
    k_gemm1<<<518, 256, 0, stream>>>(qb, W_off, W_param, b_off, b_param, offs, params);
    k_sample_mix<<<2400, 256, 0, stream>>>(offs, xyzr, featT, params, hbuf);
    k_gemm_out<<<640, 256, 0, stream>>>(hbuf, Wot, kpart);
    k_ln_out<<<600, 256, 0, stream>>>(kpart, queries, b_out, gamma, beta, out);
}